// Round 11
// baseline (260.769 us; speedup 1.0000x reference)
//
#include <hip/hip_runtime.h>
#include <stdint.h>

typedef _Float16 half8 __attribute__((ext_vector_type(8)));
typedef float f32x4 __attribute__((ext_vector_type(4)));

#define DDIM 256
#define NROWS 16384
#define KCB 8192
#define KSPLIT 4
#define KC 2048
#define ND 4194304

// async global -> LDS, 16 bytes per lane (dest = wave-uniform base + lane*16)
__device__ __forceinline__ void gll16(const void* g, void* l) {
    __builtin_amdgcn_global_load_lds(
        (const __attribute__((address_space(1))) unsigned int*)g,
        (__attribute__((address_space(3))) unsigned int*)l, 16, 0, 0);
}

__device__ __forceinline__ unsigned short f2h(float x) {
    union { _Float16 h; unsigned short u; } c;
    c.h = (_Float16)x;   // RNE
    return c.u;
}

// ---------------- fused: convert z->fp16, cb->fp16 + codebook norms ----------------
__global__ void k_prep(const float* __restrict__ z, const float* __restrict__ cb,
                       unsigned short* __restrict__ zf, unsigned short* __restrict__ ef,
                       float* __restrict__ norms) {
    const int b = blockIdx.x, t = threadIdx.x;
    const bool isz = (b < 4096);
    const float* src = isz ? z : cb;
    unsigned short* dst = isz ? zf : ef;
    const int i = (isz ? b : (b - 4096)) * 256 + t;
    float4 v = reinterpret_cast<const float4*>(src)[i];
    ushort4 h;
    h.x = f2h(v.x); h.y = f2h(v.y); h.z = f2h(v.z); h.w = f2h(v.w);
    reinterpret_cast<ushort4*>(dst)[i] = h;
    if (!isz) {
        float s = v.x * v.x + v.y * v.y + v.z * v.z + v.w * v.w;
#pragma unroll
        for (int off = 32; off > 0; off >>= 1) s += __shfl_xor(s, off, 64);
        if ((t & 63) == 0) norms[i >> 6] = s;
    }
}

// ---------------- fp16 single-pass MFMA score + top-3 argmin ----------------
// approx score(n,k) = ||e_k||^2 - 2*(z_f16 . e_f16); exact rescore downstream
__launch_bounds__(256, 3)
__global__ void k_score(const unsigned short* __restrict__ zf, const unsigned short* __restrict__ ef,
                        const float* __restrict__ norms, int* __restrict__ cand_idx) {
    __shared__ char smem[40960];   // 4 staging buffers (8 KB) + norms (8 KB)

    const int rb = blockIdx.x;     // row block 0..127
    const int ks = blockIdx.y;     // codebook split 0..3
    const int t = threadIdx.x, w = t >> 6, lane = t & 63;
    const int l15 = lane & 15, l4 = lane >> 4;

    // staging: thread t -> col colq (and colq+32), slot c = t&7; source chunk g = c ^ (col&7)
    const int colq = t >> 3;
    const int voff0 = colq * 512 + (((t & 7) ^ (colq & 7)) * 16);

    // B-fragment LDS read offsets (col = l15 within frag, 16B slot X = kc*4+l4, swizzle ^ (col&7))
    int voffB[2];
#pragma unroll
    for (int kc = 0; kc < 2; ++kc)
        voffB[kc] = l15 * 128 + ((((kc * 4) + l4) ^ (lane & 7)) * 16);

    // A in registers: wave owns rows rb*128 + w*32 .. +32 (2 rfrags of 16), fp16
    half8 A[2][8];
    {
        const size_t base0 = ((size_t)(rb * 128 + w * 32 + l15)) * DDIM + l4 * 8;
#pragma unroll
        for (int r = 0; r < 2; ++r)
#pragma unroll
            for (int kk = 0; kk < 8; ++kk)
                A[r][kk] = *reinterpret_cast<const half8*>(zf + base0 + r * 16 * DDIM + kk * 32);
    }
#pragma unroll
    for (int r = 0; r < 2; ++r)
#pragma unroll
        for (int kk = 0; kk < 8; ++kk)
            asm volatile("" : "+v"(A[r][kk]));   // pin: no remat/reload in loop

    const char* pe = (const char*)ef + (size_t)(ks * KC) * 512;

    // norms for this quarter -> LDS (read later via lgkmcnt; stays OUT of the vmcnt queue)
    gll16((const char*)(norms + ks * KC) + t * 16,        smem + 32768 + t * 16);
    gll16((const char*)(norms + ks * KC) + 4096 + t * 16, smem + 32768 + 4096 + t * 16);

    // stage global step s (64 cols x 64 d fp16) into buffer s&3 (2 loads = 1 batch)
    auto stage = [&](int s) {
        const int off = (s >> 2) * 32768 + (s & 3) * 128;
        char* sdst = smem + (s & 3) * 8192 + t * 16;
        gll16(pe + off + voff0,         sdst);
        gll16(pe + off + voff0 + 16384, sdst + 4096);
    };

    // per-lane top3 over 8 (row-slot) cells; i1,i2 packed in pk, i3 separate
    float v1[8], v2[8], v3[8]; unsigned pk[8]; int i3[8];
#pragma unroll
    for (int s = 0; s < 8; ++s) { v1[s] = 3.4e38f; v2[s] = 3.4e38f; v3[s] = 3.4e38f; pk[s] = 0; i3[s] = 0; }

    f32x4 acc[2][4];

    auto compute = [&](int dc) {
        const char* cb0 = smem + dc * 8192;
        __builtin_amdgcn_s_setprio(1);
#pragma unroll
        for (int cf = 0; cf < 4; ++cf) {
#pragma unroll
            for (int kc = 0; kc < 2; ++kc) {
                half8 b = *reinterpret_cast<const half8*>(cb0 + cf * 2048 + voffB[kc]);
                const int kk = dc * 2 + kc;
#pragma unroll
                for (int r = 0; r < 2; ++r)
                    acc[r][cf] = __builtin_amdgcn_mfma_f32_16x16x32_f16(A[r][kk], b, acc[r][cf], 0, 0, 0);
            }
        }
        __builtin_amdgcn_s_setprio(0);
    };

    // fold: insert ALL 4 col-scores per slot into top-3 (no lossy pre-min)
    auto fold = [&](int ct) {
        const float* nl = reinterpret_cast<const float*>(smem + 32768);
        const int nb0 = ct * 64 + l15;
        float nn[4];
#pragma unroll
        for (int c = 0; c < 4; ++c) nn[c] = nl[nb0 + c * 16];
#pragma unroll
        for (int r = 0; r < 2; ++r)
#pragma unroll
            for (int reg = 0; reg < 4; ++reg) {
                const int s = r * 4 + reg;
#pragma unroll
                for (int c = 0; c < 4; ++c) {
                    const float val = fmaf(-2.f, acc[r][c][reg], nn[c]);
                    const int idx = nb0 + c * 16;
                    const bool L1 = val < v1[s], L2 = val < v2[s], L3 = val < v3[s];
                    const int oi1 = (int)(pk[s] & 0xFFFFu), oi2 = (int)(pk[s] >> 16);
                    i3[s] = L2 ? oi2 : (L3 ? idx : i3[s]);
                    v3[s] = L2 ? v2[s] : (L3 ? val : v3[s]);
                    const int ni2 = L1 ? oi1 : (L2 ? idx : oi2);
                    v2[s] = L1 ? v1[s] : (L2 ? val : v2[s]);
                    const int ni1 = L1 ? idx : oi1;
                    v1[s] = L1 ? val : v1[s];
                    pk[s] = (unsigned)ni1 | ((unsigned)ni2 << 16);
                }
            }
    };

#define ACC_ZERO() do { \
    _Pragma("unroll") for (int r = 0; r < 2; ++r) \
    _Pragma("unroll") for (int cf = 0; cf < 4; ++cf) acc[r][cf] = (f32x4){0.f,0.f,0.f,0.f}; } while (0)

#define SYNC_V4()  do { asm volatile("s_waitcnt vmcnt(4) lgkmcnt(0)" ::: "memory"); \
    __builtin_amdgcn_sched_barrier(0); __builtin_amdgcn_s_barrier(); } while (0)
#define SYNC_V2()  do { asm volatile("s_waitcnt vmcnt(2) lgkmcnt(0)" ::: "memory"); \
    __builtin_amdgcn_sched_barrier(0); __builtin_amdgcn_s_barrier(); } while (0)
#define SYNC_V0()  do { asm volatile("s_waitcnt vmcnt(0) lgkmcnt(0)" ::: "memory"); \
    __builtin_amdgcn_sched_barrier(0); __builtin_amdgcn_s_barrier(); } while (0)

    // prologue: A-loads + norms + batches 0,1,2 in queue; wait all but batches 1,2
    stage(0); stage(1); stage(2);
    asm volatile("s_waitcnt vmcnt(4)" ::: "memory");
    __builtin_amdgcn_sched_barrier(0);
    __builtin_amdgcn_s_barrier();

#pragma unroll 1
    for (int ct = 0; ct < 31; ++ct) {
        ACC_ZERO();
        const int s0 = ct * 4;
#pragma unroll
        for (int dc = 0; dc < 4; ++dc) {
            stage(s0 + dc + 3);
            compute(dc);
            SYNC_V4();
        }
        fold(ct);
    }
    // ct = 31 tail: steps 124..127
    ACC_ZERO();
    stage(127); compute(0); SYNC_V4();
    compute(1);             SYNC_V2();
    compute(2);             SYNC_V0();
    compute(3);
    fold(31);

    // ---- butterfly top3 merge across the 16 column-lanes (l15); l4 preserved ----
#pragma unroll
    for (int m = 1; m < 16; m <<= 1) {
#pragma unroll
        for (int s = 0; s < 8; ++s) {
            const float a1v = v1[s], a2v = v2[s], a3v = v3[s];
            const int a1i = (int)(pk[s] & 0xFFFFu), a2i = (int)(pk[s] >> 16), a3i = i3[s];
            const float b1v = __shfl_xor(a1v, m, 64), b2v = __shfl_xor(a2v, m, 64), b3v = __shfl_xor(a3v, m, 64);
            const unsigned opk = (unsigned)__shfl_xor((int)pk[s], m, 64);
            const int b1i = (int)(opk & 0xFFFFu), b2i = (int)(opk >> 16), b3i = __shfl_xor(a3i, m, 64);
            auto lt = [](float va, int ia, float vb, int ib) { return va < vb || (va == vb && ia < ib); };
            const bool w1 = lt(a1v, a1i, b1v, b1i);
            const float c1v = w1 ? a1v : b1v; const int c1i = w1 ? a1i : b1i;
            const float xav = w1 ? a2v : a1v; const int xai = w1 ? a2i : a1i;
            const float xbv = w1 ? b1v : b2v; const int xbi = w1 ? b1i : b2i;
            const bool w2 = lt(xav, xai, xbv, xbi);
            const float c2v = w2 ? xav : xbv; const int c2i = w2 ? xai : xbi;
            const float yav = w1 ? (w2 ? a3v : a2v) : (w2 ? a2v : a1v);
            const int   yai = w1 ? (w2 ? a3i : a2i) : (w2 ? a2i : a1i);
            const float ybv = w1 ? (w2 ? b1v : b2v) : (w2 ? b2v : b3v);
            const int   ybi = w1 ? (w2 ? b1i : b2i) : (w2 ? b2i : b3i);
            const bool w3 = lt(yav, yai, ybv, ybi);
            v1[s] = c1v; v2[s] = c2v; v3[s] = w3 ? yav : ybv;
            pk[s] = (unsigned)c1i | ((unsigned)c2i << 16);
            i3[s] = w3 ? yai : ybi;
        }
    }
    if (l15 == 0) {
#pragma unroll
        for (int s = 0; s < 8; ++s) {
            const int row = (s >> 2) * 16 + l4 * 4 + (s & 3);
            const int n = rb * 128 + w * 32 + row;
            const int base = n * 12 + ks * 3;
            cand_idx[base + 0] = ks * KC + (int)(pk[s] & 0xFFFFu);
            cand_idx[base + 1] = ks * KC + (int)(pk[s] >> 16);
            cand_idx[base + 2] = ks * KC + i3[s];
        }
    }
}

// ---------------- exact fp32 rescore of all 12 candidates ----------------
// one wave per row; grid = 4096 blocks of 256. MUST complete before k_finalize
// (k_finalize's z_e writes overwrite the scratch region carved from d_out).
__global__ void k_merge(const float* __restrict__ z, const float* __restrict__ cb,
                        const float* __restrict__ norms, const int* __restrict__ cand_idx,
                        int* __restrict__ fidx) {
    const int gid = blockIdx.x * blockDim.x + threadIdx.x;
    const int wid = gid >> 6;          // row id 0..16383
    const int lane = threadIdx.x & 63;
    int ii[12];
#pragma unroll
    for (int c = 0; c < 12; ++c) ii[c] = cand_idx[wid * 12 + c] & (KCB - 1);
    const float4 zq = *reinterpret_cast<const float4*>(z + (size_t)wid * DDIM + lane * 4);
    float d[12];
#pragma unroll
    for (int c = 0; c < 12; ++c) {
        const float4 e4 = *reinterpret_cast<const float4*>(cb + (size_t)ii[c] * DDIM + lane * 4);
        d[c] = zq.x * e4.x + zq.y * e4.y + zq.z * e4.z + zq.w * e4.w;
    }
#pragma unroll
    for (int m = 32; m > 0; m >>= 1)
#pragma unroll
        for (int c = 0; c < 12; ++c) d[c] += __shfl_xor(d[c], m, 64);
    float bv = 3.4e38f; int bi = 0;
#pragma unroll
    for (int c = 0; c < 12; ++c) {
        const float s = norms[ii[c]] - 2.f * d[c];
        if (s < bv || (s == bv && ii[c] < bi)) { bv = s; bi = ii[c]; }
    }
    if (lane == 0) fidx[wid] = bi;
}

// ---------------- copy z_e, gather z_q, loss partials ----------------
__global__ void k_finalize(const float* __restrict__ z, const float* __restrict__ cb,
                           const int* __restrict__ fidx, float* __restrict__ out,
                           float* __restrict__ partials) {
    const int i4 = blockIdx.x * blockDim.x + threadIdx.x;
    float4 zv = *reinterpret_cast<const float4*>(z + (size_t)i4 * 4);
    *reinterpret_cast<float4*>(out + (size_t)i4 * 4) = zv;
    const int n = i4 >> 6;
    const int d0 = (i4 & 63) << 2;
    const int idx = fidx[n] & (KCB - 1);
    float4 q = *reinterpret_cast<const float4*>(cb + (size_t)idx * DDIM + d0);
    float* oq = out + (size_t)ND + 1 + (size_t)i4 * 4;
    oq[0] = q.x; oq[1] = q.y; oq[2] = q.z; oq[3] = q.w;
    const float dx = q.x - zv.x, dy = q.y - zv.y, dz = q.z - zv.z, dw = q.w - zv.w;
    float s = dx * dx + dy * dy + dz * dz + dw * dw;
#pragma unroll
    for (int off = 32; off > 0; off >>= 1) s += __shfl_xor(s, off, 64);
    __shared__ float sm[4];
    const int wv = threadIdx.x >> 6, ln = threadIdx.x & 63;
    if (ln == 0) sm[wv] = s;
    __syncthreads();
    if (threadIdx.x == 0) partials[blockIdx.x] = sm[0] + sm[1] + sm[2] + sm[3];
}

__global__ void k_loss(const float* __restrict__ partials, float* __restrict__ out) {
    float s = 0.f;
    for (int i = threadIdx.x; i < 4096; i += 256) s += partials[i];
#pragma unroll
    for (int off = 32; off > 0; off >>= 1) s += __shfl_xor(s, off, 64);
    __shared__ float sm[4];
    const int wv = threadIdx.x >> 6, ln = threadIdx.x & 63;
    if (ln == 0) sm[wv] = s;
    __syncthreads();
    if (threadIdx.x == 0) out[ND] = 2.0f * (sm[0] + sm[1] + sm[2] + sm[3]) / (float)ND;
}

extern "C" void kernel_launch(void* const* d_in, const int* in_sizes, int n_in,
                              void* d_out, int out_size, void* d_ws, size_t ws_size,
                              hipStream_t stream) {
    const float* z = (const float*)d_in[0];   // [16384, 256]
    const float* cb = (const float*)d_in[1];  // [8192, 256]
    float* out = (float*)d_out;               // z_e[ND], loss[1], z_q[ND]
    float* ws = (float*)d_ws;

    // small scratch in ws (~115 KB)
    float* norms = ws;                        // 8192
    int* fidx = (int*)(ws + 8192);            // 16384
    float* partials = ws + 8192 + 16384;      // 4096

    // big scratch carved from d_out (33.55 MB; all consumed by k_merge BEFORE
    // k_finalize overwrites d_out with the real outputs)
    char* ob = (char*)d_out;
    unsigned short* zf = (unsigned short*)(ob);                     // 8.39 MB fp16 z
    unsigned short* ef = (unsigned short*)(ob + 8388608);           // 4.19 MB fp16 cb
    int* cand_idx = (int*)(ob + 12582912);                          // 786 KB (ends 13.4 MB)

    k_prep<<<dim3(6144), dim3(256), 0, stream>>>(z, cb, zf, ef, norms);
    k_score<<<dim3(128, 4), dim3(256), 0, stream>>>(zf, ef, norms, cand_idx);
    k_merge<<<dim3(4096), dim3(256), 0, stream>>>(z, cb, norms, cand_idx, fidx);
    k_finalize<<<dim3(4096), dim3(256), 0, stream>>>(z, cb, fidx, out, partials);
    k_loss<<<dim3(1), dim3(256), 0, stream>>>(partials, out);
}